// Round 1
// baseline (1451.640 us; speedup 1.0000x reference)
//
#include <hip/hip_runtime.h>
#include <cmath>

#define LEAKY(v) ((v) > 0.f ? (v) : 0.2f*(v))

// ---------------- CSR build ----------------

__global__ void deg_kernel(const int* __restrict__ dst, int* __restrict__ degi, int E){
  int e = blockIdx.x*256 + threadIdx.x;
  if (e < E) atomicAdd(&degi[dst[e]], 1);
}

__global__ void scan_kernel(const int* __restrict__ degi, int* __restrict__ row_off, int N){
  __shared__ int part[1024];
  int t = threadIdx.x;
  int chunk = (N + 1023) >> 10;
  int s0 = t*chunk, s1 = min(s0 + chunk, N);
  int sum = 0;
  for (int i = s0; i < s1; i++) sum += degi[i];
  part[t] = sum; __syncthreads();
  for (int off = 1; off < 1024; off <<= 1){
    int v = (t >= off) ? part[t - off] : 0;
    __syncthreads();
    part[t] += v;
    __syncthreads();
  }
  int run = (t == 0) ? 0 : part[t-1];
  for (int i = s0; i < s1; i++){ row_off[i] = run; run += degi[i]; }
  if (t == 1023) row_off[N] = run;
}

__global__ void scatter_kernel(const int* __restrict__ src, const int* __restrict__ dst,
                               const int* __restrict__ row_off, int* __restrict__ cursor,
                               int* __restrict__ csr_src, int* __restrict__ csr_dst, int E){
  int e = blockIdx.x*256 + threadIdx.x;
  if (e < E){
    int d = dst[e];
    int pos = row_off[d] + atomicAdd(&cursor[d], 1);
    csr_src[pos] = src[e];
    csr_dst[pos] = d;
  }
}

// ---------------- GEMM: O[N,M] = X[N,K] @ W[K,M], M multiple of 64 ----------------

__global__ __launch_bounds__(256) void gemm_kernel(const float* __restrict__ X,
                                                   const float* __restrict__ W,
                                                   float* __restrict__ O,
                                                   int N, int K, int M){
  __shared__ float xs[32*256];
  int t = threadIdx.x;
  int nt = blockIdx.x, ct = blockIdx.y;
  int col = ct*64 + (t & 63);
  int g = t >> 6;
  for (int idx = t; idx < 32*K; idx += 256){
    int r = idx / K, k = idx - r*K;
    int n = nt*32 + r;
    xs[idx] = (n < N) ? X[(size_t)n*K + k] : 0.f;
  }
  __syncthreads();
  float acc[8] = {0,0,0,0,0,0,0,0};
  const float* xrow = &xs[(size_t)g*8*K];
  for (int k = 0; k < K; k++){
    float w = W[(size_t)k*M + col];
    #pragma unroll
    for (int i = 0; i < 8; i++) acc[i] += xrow[(size_t)i*K + k] * w;
  }
  #pragma unroll
  for (int i = 0; i < 8; i++){
    int n = nt*32 + g*8 + i;
    if (n < N) O[(size_t)n*M + col] = acc[i];
  }
}

// ---------------- edge logits, C=128, H in {1,2}: one wave per (edge,head) ----------------

template<int H>
__global__ __launch_bounds__(256) void logits_kernel(const int* __restrict__ csr_src,
                                                     const int* __restrict__ csr_dst,
                                                     const float* __restrict__ xl,
                                                     const float* __restrict__ xr,
                                                     const float* __restrict__ att,
                                                     float* __restrict__ logits, int E){
  int wid = blockIdx.x*4 + (threadIdx.x >> 6);
  int lane = threadIdx.x & 63;
  int pos = (H == 2) ? (wid >> 1) : wid;
  int h   = (H == 2) ? (wid & 1) : 0;
  if (pos >= E) return;
  int s = csr_src[pos], d = csr_dst[pos];
  const int HC = H*128;
  const float* pl = xl + (size_t)s*HC + h*128;
  const float* pr = xr + (size_t)d*HC + h*128;
  const float* pa = att + h*128;
  float sum = 0.f;
  #pragma unroll
  for (int c = lane; c < 128; c += 64){
    float v = pl[c] + pr[c];
    v = LEAKY(v);
    sum += v * pa[c];
  }
  #pragma unroll
  for (int off = 32; off > 0; off >>= 1) sum += __shfl_down(sum, off);
  if (lane == 0) logits[(size_t)pos*H + h] = sum;
}

// ---------------- per-node softmax + weighted mean aggregation, C=128 ----------------

template<int H>
__global__ void aggr_kernel(const int* __restrict__ row_off, const int* __restrict__ csr_src,
                            const float* __restrict__ xl, const float* __restrict__ logits,
                            const float* __restrict__ bias, float* __restrict__ out, int N){
  const int T = H*128;
  int n = blockIdx.x;
  int t = threadIdx.x;
  int r0 = row_off[n], r1 = row_off[n+1];
  int deg = r1 - r0;
  __shared__ float sred[256];
  __shared__ float smax[2];
  __shared__ float sden[2];
  __shared__ float s_alpha[2][64];
  __shared__ int s_src[64];

  // phase 1: per-head max
  float lm[H];
  #pragma unroll
  for (int h = 0; h < H; h++) lm[h] = -INFINITY;
  for (int pos = r0 + t; pos < r1; pos += T){
    #pragma unroll
    for (int h = 0; h < H; h++) lm[h] = fmaxf(lm[h], logits[(size_t)pos*H + h]);
  }
  for (int h = 0; h < H; h++){
    sred[t] = lm[h]; __syncthreads();
    for (int off = T >> 1; off > 0; off >>= 1){
      if (t < off) sred[t] = fmaxf(sred[t], sred[t + off]);
      __syncthreads();
    }
    if (t == 0) smax[h] = sred[0];
    __syncthreads();
  }

  // phase 2: per-head denom
  float ld[H];
  #pragma unroll
  for (int h = 0; h < H; h++) ld[h] = 0.f;
  for (int pos = r0 + t; pos < r1; pos += T){
    #pragma unroll
    for (int h = 0; h < H; h++) ld[h] += expf(logits[(size_t)pos*H + h] - smax[h]);
  }
  for (int h = 0; h < H; h++){
    sred[t] = ld[h]; __syncthreads();
    for (int off = T >> 1; off > 0; off >>= 1){
      if (t < off) sred[t] += sred[t + off];
      __syncthreads();
    }
    if (t == 0) sden[h] = sred[0];
    __syncthreads();
  }

  // phase 3: weighted message accumulation in 64-edge chunks
  float acc = 0.f;
  int h = (H == 2) ? (t >> 7) : 0;
  int c = t & 127;
  for (int base = r0; base < r1; base += 64){
    int cnt = min(64, r1 - base);
    if (t < cnt){
      int pos = base + t;
      s_src[t] = csr_src[pos];
      #pragma unroll
      for (int hh = 0; hh < H; hh++)
        s_alpha[hh][t] = expf(logits[(size_t)pos*H + hh] - smax[hh]) / sden[hh];
    }
    __syncthreads();
    for (int j = 0; j < cnt; j++)
      acc += s_alpha[h][j] * xl[(size_t)s_src[j]*T + h*128 + c];
    __syncthreads();
  }
  float degf = (float)(deg > 0 ? deg : 1);
  out[(size_t)n*T + t] = acc/degf + bias[t];
}

// ---------------- layer 3 (C=1) specials ----------------

__global__ __launch_bounds__(256) void gemm3_kernel(const float* __restrict__ h2,
                                                    const float* __restrict__ W3l,
                                                    const float* __restrict__ W3r,
                                                    float* __restrict__ xl3,
                                                    float* __restrict__ xr3, int N){
  int n = blockIdx.x*4 + (threadIdx.x >> 6);
  int lane = threadIdx.x & 63;
  if (n >= N) return;
  float v1 = h2[(size_t)n*128 + lane];
  float v2 = h2[(size_t)n*128 + 64 + lane];
  float al = v1*W3l[lane] + v2*W3l[64 + lane];
  float ar = v1*W3r[lane] + v2*W3r[64 + lane];
  #pragma unroll
  for (int off = 32; off > 0; off >>= 1){
    al += __shfl_down(al, off);
    ar += __shfl_down(ar, off);
  }
  if (lane == 0){ xl3[n] = al; xr3[n] = ar; }
}

__global__ void logits3_kernel(const int* __restrict__ csr_src, const int* __restrict__ csr_dst,
                               const float* __restrict__ xl3, const float* __restrict__ xr3,
                               const float* __restrict__ a3, float* __restrict__ logits, int E){
  int e = blockIdx.x*256 + threadIdx.x;
  if (e >= E) return;
  float v = xl3[csr_src[e]] + xr3[csr_dst[e]];
  v = LEAKY(v);
  logits[e] = v * a3[0];
}

__global__ void aggr3_kernel(const int* __restrict__ row_off, const int* __restrict__ csr_src,
                             const float* __restrict__ xl3, const float* __restrict__ logits,
                             const float* __restrict__ b3, float* __restrict__ h3, int N){
  int n = blockIdx.x*256 + threadIdx.x;
  if (n >= N) return;
  int r0 = row_off[n], r1 = row_off[n+1];
  int deg = r1 - r0;
  float b = b3[0];
  if (deg == 0){ h3[n] = b; return; }
  float m = -INFINITY;
  for (int p = r0; p < r1; p++) m = fmaxf(m, logits[p]);
  float den = 0.f, s = 0.f;
  for (int p = r0; p < r1; p++){
    float a = expf(logits[p] - m);
    den += a;
    s += a * xl3[csr_src[p]];
  }
  h3[n] = s/den/(float)deg + b;
}

__global__ void out_kernel(const float* __restrict__ h3, const float* __restrict__ y,
                           const int* __restrict__ tidx, float* __restrict__ out, int T){
  int i = blockIdx.x*256 + threadIdx.x;
  if (i >= T) return;
  int n = tidx[i];
  out[i] = 1.f/(1.f + expf(-h3[n]));
  out[T + i] = y[n];
}

// ---------------- launch ----------------

extern "C" void kernel_launch(void* const* d_in, const int* in_sizes, int n_in,
                              void* d_out, int out_size, void* d_ws, size_t ws_size,
                              hipStream_t stream){
  const float* x    = (const float*)d_in[0];
  const int*   ei   = (const int*)d_in[1];
  const float* y    = (const float*)d_in[2];
  const int*   tidx = (const int*)d_in[3];
  const float* W1l  = (const float*)d_in[4];
  const float* W1r  = (const float*)d_in[5];
  const float* a1   = (const float*)d_in[6];
  const float* b1   = (const float*)d_in[7];
  const float* W2l  = (const float*)d_in[8];
  const float* W2r  = (const float*)d_in[9];
  const float* a2   = (const float*)d_in[10];
  const float* b2   = (const float*)d_in[11];
  const float* W3l  = (const float*)d_in[12];
  const float* W3r  = (const float*)d_in[13];
  const float* a3   = (const float*)d_in[14];
  const float* b3   = (const float*)d_in[15];

  int N = in_sizes[2];        // 50000 nodes
  int E = in_sizes[1] / 2;    // 800000 edges
  int T = in_sizes[3];        // 40000 train indices
  const int* src = ei;
  const int* dst = ei + E;

  char* w = (char*)d_ws;
  size_t off = 0;
  auto take = [&](size_t bytes) -> char* {
    char* p = w + off;
    off = (off + bytes + 255) & ~(size_t)255;
    return p;
  };
  int*   row_off = (int*)  take((size_t)(N+1)*4);
  int*   degi    = (int*)  take((size_t)N*4);
  int*   cursor  = (int*)  take((size_t)N*4);
  int*   csr_src = (int*)  take((size_t)E*4);
  int*   csr_dst = (int*)  take((size_t)E*4);
  float* logits  = (float*)take((size_t)E*2*4);
  float* A       = (float*)take((size_t)N*256*4);
  float* B       = (float*)take((size_t)N*256*4);

  // ---- CSR build (graph shared by all 3 layers) ----
  hipMemsetAsync(degi, 0, (size_t)N*4, stream);
  hipMemsetAsync(cursor, 0, (size_t)N*4, stream);
  deg_kernel<<<(E+255)/256, 256, 0, stream>>>(dst, degi, E);
  scan_kernel<<<1, 1024, 0, stream>>>(degi, row_off, N);
  scatter_kernel<<<(E+255)/256, 256, 0, stream>>>(src, dst, row_off, cursor, csr_src, csr_dst, E);

  // ---- layer 1: 129 -> 256 (H=2, C=128) ----
  // xl1 = A, xr1 = B, h1 overwrites B (xr dead after logits)
  gemm_kernel<<<dim3((N+31)/32, 4), 256, 0, stream>>>(x, W1l, A, N, 129, 256);
  gemm_kernel<<<dim3((N+31)/32, 4), 256, 0, stream>>>(x, W1r, B, N, 129, 256);
  logits_kernel<2><<<(2*E+3)/4, 256, 0, stream>>>(csr_src, csr_dst, A, B, a1, logits, E);
  aggr_kernel<2><<<N, 256, 0, stream>>>(row_off, csr_src, A, logits, b1, B, N);
  float* h1 = B;

  // ---- layer 2: 256 -> 128 (H=1, C=128) ----
  // xl2 = A[0:N*128], xr2 = A[N*128:], h2 overwrites B[0:N*128]
  float* xl2 = A;
  float* xr2 = A + (size_t)N*128;
  gemm_kernel<<<dim3((N+31)/32, 2), 256, 0, stream>>>(h1, W2l, xl2, N, 256, 128);
  gemm_kernel<<<dim3((N+31)/32, 2), 256, 0, stream>>>(h1, W2r, xr2, N, 256, 128);
  logits_kernel<1><<<(E+3)/4, 256, 0, stream>>>(csr_src, csr_dst, xl2, xr2, a2, logits, E);
  float* h2 = B;
  aggr_kernel<1><<<N, 128, 0, stream>>>(row_off, csr_src, xl2, logits, b2, h2, N);

  // ---- layer 3: 128 -> 1 (H=1, C=1) ----
  float* xl3 = A;
  float* xr3 = A + N;
  float* h3  = A + 2*(size_t)N;
  gemm3_kernel<<<(N+3)/4, 256, 0, stream>>>(h2, W3l, W3r, xl3, xr3, N);
  logits3_kernel<<<(E+255)/256, 256, 0, stream>>>(csr_src, csr_dst, xl3, xr3, a3, logits, E);
  aggr3_kernel<<<(N+255)/256, 256, 0, stream>>>(row_off, csr_src, xl3, logits, b3, h3, N);

  // ---- output: (sigmoid(h3)[tidx], y[tidx]) ----
  out_kernel<<<(T+255)/256, 256, 0, stream>>>(h3, y, tidx, (float*)d_out, T);
}

// Round 2
// 1201.017 us; speedup vs baseline: 1.2087x; 1.2087x over previous
//
#include <hip/hip_runtime.h>
#include <cmath>

#define LEAKY(v) ((v) > 0.f ? (v) : 0.2f*(v))

// ---------------- CSR build ----------------

__global__ void deg_kernel(const int* __restrict__ dst, int* __restrict__ degi, int E){
  int e = blockIdx.x*256 + threadIdx.x;
  if (e < E) atomicAdd(&degi[dst[e]], 1);
}

__global__ void scan_kernel(const int* __restrict__ degi, int* __restrict__ row_off, int N){
  __shared__ int part[1024];
  int t = threadIdx.x;
  int chunk = (N + 1023) >> 10;
  int s0 = t*chunk, s1 = min(s0 + chunk, N);
  int sum = 0;
  for (int i = s0; i < s1; i++) sum += degi[i];
  part[t] = sum; __syncthreads();
  for (int off = 1; off < 1024; off <<= 1){
    int v = (t >= off) ? part[t - off] : 0;
    __syncthreads();
    part[t] += v;
    __syncthreads();
  }
  int run = (t == 0) ? 0 : part[t-1];
  for (int i = s0; i < s1; i++){ row_off[i] = run; run += degi[i]; }
  if (t == 1023) row_off[N] = run;
}

__global__ void scatter_kernel(const int* __restrict__ src, const int* __restrict__ dst,
                               const int* __restrict__ row_off, int* __restrict__ cursor,
                               int* __restrict__ csr_src, int E){
  int e = blockIdx.x*256 + threadIdx.x;
  if (e < E){
    int d = dst[e];
    int pos = row_off[d] + atomicAdd(&cursor[d], 1);
    csr_src[pos] = src[e];
  }
}

// ---------------- GEMM: O[N,M] = X[N,K] @ W[K,M], 64x64 tile, 4x4 microtile ----------------

__global__ __launch_bounds__(256) void gemm_kernel(const float* __restrict__ X,
                                                   const float* __restrict__ W,
                                                   float* __restrict__ O,
                                                   int N, int K, int M){
  __shared__ float Xs[32][65];   // [k][r], stride 65 -> conflict-free transposed store
  __shared__ float Ws[32][64];   // [k][c]
  int t = threadIdx.x;
  int n0 = blockIdx.x*64, c0 = blockIdx.y*64;
  int tx = t & 15, ty = t >> 4;
  float acc[4][4];
  #pragma unroll
  for (int i = 0; i < 4; i++)
    #pragma unroll
    for (int j = 0; j < 4; j++) acc[i][j] = 0.f;

  for (int k0 = 0; k0 < K; k0 += 32){
    for (int idx = t; idx < 2048; idx += 256){
      int r = idx >> 5, kk = idx & 31;
      int n = n0 + r, k = k0 + kk;
      Xs[kk][r] = (n < N && k < K) ? X[(size_t)n*K + k] : 0.f;
    }
    for (int idx = t; idx < 2048; idx += 256){
      int kk = idx >> 6, c = idx & 63;
      int k = k0 + kk;
      Ws[kk][c] = (k < K) ? W[(size_t)k*M + c0 + c] : 0.f;
    }
    __syncthreads();
    #pragma unroll
    for (int kk = 0; kk < 32; kk++){
      float4 wv = *(const float4*)&Ws[kk][tx*4];
      float x0 = Xs[kk][ty*4+0];
      float x1 = Xs[kk][ty*4+1];
      float x2 = Xs[kk][ty*4+2];
      float x3 = Xs[kk][ty*4+3];
      acc[0][0] += x0*wv.x; acc[0][1] += x0*wv.y; acc[0][2] += x0*wv.z; acc[0][3] += x0*wv.w;
      acc[1][0] += x1*wv.x; acc[1][1] += x1*wv.y; acc[1][2] += x1*wv.z; acc[1][3] += x1*wv.w;
      acc[2][0] += x2*wv.x; acc[2][1] += x2*wv.y; acc[2][2] += x2*wv.z; acc[2][3] += x2*wv.w;
      acc[3][0] += x3*wv.x; acc[3][1] += x3*wv.y; acc[3][2] += x3*wv.z; acc[3][3] += x3*wv.w;
    }
    __syncthreads();
  }
  #pragma unroll
  for (int i = 0; i < 4; i++){
    int n = n0 + ty*4 + i;
    if (n < N){
      float4 v;
      v.x = acc[i][0]; v.y = acc[i][1]; v.z = acc[i][2]; v.w = acc[i][3];
      *(float4*)&O[(size_t)n*M + c0 + tx*4] = v;
    }
  }
}

// ---------------- fused GATv2 edge phase: logits + online softmax + weighted mean ----------------
// One block per dst node. xl gathered ONCE per edge (staged in LDS, reused for message).
// out may alias xr: block n only reads xr[n] (into LDS at start) and only writes out[n].

template<int H>
__global__ __launch_bounds__(H*128) void fused_gat_kernel(
    const int* __restrict__ row_off, const int* __restrict__ csr_src,
    const float* __restrict__ xl, const float* __restrict__ xr,
    const float* __restrict__ att, const float* __restrict__ bias,
    float* __restrict__ out, int N)
{
  constexpr int CH = H*128;     // channels == blockDim.x
  constexpr int NW = CH/64;     // waves per block
  constexpr int CHUNK = 32;
  __shared__ float s_xl[CHUNK][CH];
  __shared__ float s_xr[CH];
  __shared__ float s_att[CH];
  __shared__ float s_logit[H][CHUNK];
  __shared__ float s_w[H][CHUNK];
  __shared__ float s_ml[H], s_ll[H], s_scale[H];

  int n = blockIdx.x;
  int t = threadIdx.x;
  int wv = t >> 6, lane = t & 63;
  int r0 = row_off[n], r1 = row_off[n+1];
  s_xr[t] = xr[(size_t)n*CH + t];
  s_att[t] = att[t];
  if (t < H){ s_ml[t] = -INFINITY; s_ll[t] = 0.f; }
  float acc = 0.f;
  int h_t = (H == 2) ? (t >> 7) : 0;
  __syncthreads();

  for (int base = r0; base < r1; base += CHUNK){
    int cnt = min(CHUNK, r1 - base);
    // phase A: logits + stage xl[src] into LDS (single gather per edge)
    for (int j = wv; j < cnt; j += NW){
      int s = csr_src[base + j];
      const float2* px = (const float2*)(xl + (size_t)s*CH);
      float2* pl = (float2*)&s_xl[j][0];
      float sum[H];
      #pragma unroll
      for (int h = 0; h < H; h++) sum[h] = 0.f;
      #pragma unroll
      for (int u = 0; u < H; u++){
        float2 v = px[u*64 + lane];
        pl[u*64 + lane] = v;
        int c = u*128 + lane*2;
        float e0 = v.x + s_xr[c];   e0 = LEAKY(e0);
        float e1 = v.y + s_xr[c+1]; e1 = LEAKY(e1);
        sum[u] += e0*s_att[c] + e1*s_att[c+1];
      }
      #pragma unroll
      for (int off = 32; off > 0; off >>= 1){
        #pragma unroll
        for (int h = 0; h < H; h++) sum[h] += __shfl_down(sum[h], off);
      }
      if (lane == 0){
        #pragma unroll
        for (int h = 0; h < H; h++) s_logit[h][j] = sum[h];
      }
    }
    __syncthreads();
    // phase B1: online-softmax bookkeeping (serial per head, <=32 elems)
    if (t < H){
      float m_old = s_ml[t];
      float cm = m_old;
      for (int j = 0; j < cnt; j++) cm = fmaxf(cm, s_logit[t][j]);
      float sc = expf(m_old - cm);       // 0 when m_old == -inf
      float l = s_ll[t] * sc;
      for (int j = 0; j < cnt; j++){
        float w = expf(s_logit[t][j] - cm);
        s_w[t][j] = w;
        l += w;
      }
      s_ll[t] = l; s_ml[t] = cm; s_scale[t] = sc;
    }
    __syncthreads();
    // phase B2: rescale + accumulate from LDS
    acc *= s_scale[h_t];
    for (int j = 0; j < cnt; j++) acc += s_w[h_t][j] * s_xl[j][t];
    __syncthreads();
  }

  int deg = r1 - r0;
  float res = bias[t];
  if (deg > 0) res += acc / (s_ll[h_t] * (float)deg);
  out[(size_t)n*CH + t] = res;
}

// ---------------- layer 3 (C=1) ----------------

__global__ __launch_bounds__(256) void gemm3_kernel(const float* __restrict__ h2,
                                                    const float* __restrict__ W3l,
                                                    const float* __restrict__ W3r,
                                                    float* __restrict__ xl3,
                                                    float* __restrict__ xr3, int N){
  int n = blockIdx.x*4 + (threadIdx.x >> 6);
  int lane = threadIdx.x & 63;
  if (n >= N) return;
  float v1 = h2[(size_t)n*128 + lane];
  float v2 = h2[(size_t)n*128 + 64 + lane];
  float al = v1*W3l[lane] + v2*W3l[64 + lane];
  float ar = v1*W3r[lane] + v2*W3r[64 + lane];
  #pragma unroll
  for (int off = 32; off > 0; off >>= 1){
    al += __shfl_down(al, off);
    ar += __shfl_down(ar, off);
  }
  if (lane == 0){ xl3[n] = al; xr3[n] = ar; }
}

// fused logits + online softmax + mean for C=1 (one thread per node, single pass)
__global__ void aggr3_kernel(const int* __restrict__ row_off, const int* __restrict__ csr_src,
                             const float* __restrict__ xl3, const float* __restrict__ xr3,
                             const float* __restrict__ a3, const float* __restrict__ b3,
                             float* __restrict__ h3, int N){
  int n = blockIdx.x*256 + threadIdx.x;
  if (n >= N) return;
  int r0 = row_off[n], r1 = row_off[n+1];
  int deg = r1 - r0;
  float b = b3[0];
  if (deg == 0){ h3[n] = b; return; }
  float xr = xr3[n];
  float aa = a3[0];
  float m = -INFINITY, den = 0.f, s = 0.f;
  for (int p = r0; p < r1; p++){
    float xlv = xl3[csr_src[p]];
    float v = xlv + xr;
    v = LEAKY(v) * aa;
    if (v > m){
      float sc = expf(m - v);   // 0 on first iter
      den *= sc; s *= sc; m = v;
    }
    float a = expf(v - m);
    den += a;
    s += a * xlv;
  }
  h3[n] = s/den/(float)deg + b;
}

__global__ void out_kernel(const float* __restrict__ h3, const float* __restrict__ y,
                           const int* __restrict__ tidx, float* __restrict__ out, int T){
  int i = blockIdx.x*256 + threadIdx.x;
  if (i >= T) return;
  int n = tidx[i];
  out[i] = 1.f/(1.f + expf(-h3[n]));
  out[T + i] = y[n];
}

// ---------------- launch ----------------

extern "C" void kernel_launch(void* const* d_in, const int* in_sizes, int n_in,
                              void* d_out, int out_size, void* d_ws, size_t ws_size,
                              hipStream_t stream){
  const float* x    = (const float*)d_in[0];
  const int*   ei   = (const int*)d_in[1];
  const float* y    = (const float*)d_in[2];
  const int*   tidx = (const int*)d_in[3];
  const float* W1l  = (const float*)d_in[4];
  const float* W1r  = (const float*)d_in[5];
  const float* a1   = (const float*)d_in[6];
  const float* b1   = (const float*)d_in[7];
  const float* W2l  = (const float*)d_in[8];
  const float* W2r  = (const float*)d_in[9];
  const float* a2   = (const float*)d_in[10];
  const float* b2   = (const float*)d_in[11];
  const float* W3l  = (const float*)d_in[12];
  const float* W3r  = (const float*)d_in[13];
  const float* a3   = (const float*)d_in[14];
  const float* b3   = (const float*)d_in[15];

  int N = in_sizes[2];        // 50000 nodes
  int E = in_sizes[1] / 2;    // 800000 edges
  int T = in_sizes[3];        // 40000 train indices
  const int* src = ei;
  const int* dst = ei + E;

  char* w = (char*)d_ws;
  size_t off = 0;
  auto take = [&](size_t bytes) -> char* {
    char* p = w + off;
    off = (off + bytes + 255) & ~(size_t)255;
    return p;
  };
  int*   row_off = (int*)  take((size_t)(N+1)*4);
  int*   degi    = (int*)  take((size_t)N*4);
  int*   cursor  = (int*)  take((size_t)N*4);
  int*   csr_src = (int*)  take((size_t)E*4);
  float* A       = (float*)take((size_t)N*256*4);
  float* B       = (float*)take((size_t)N*256*4);

  // ---- CSR build (graph shared by all 3 layers) ----
  hipMemsetAsync(degi, 0, (size_t)N*4, stream);
  hipMemsetAsync(cursor, 0, (size_t)N*4, stream);
  deg_kernel<<<(E+255)/256, 256, 0, stream>>>(dst, degi, E);
  scan_kernel<<<1, 1024, 0, stream>>>(degi, row_off, N);
  scatter_kernel<<<(E+255)/256, 256, 0, stream>>>(src, dst, row_off, cursor, csr_src, E);

  // ---- layer 1: 129 -> 256 (H=2, C=128) ----
  gemm_kernel<<<dim3((N+63)/64, 4), 256, 0, stream>>>(x, W1l, A, N, 129, 256);  // xl1 = A
  gemm_kernel<<<dim3((N+63)/64, 4), 256, 0, stream>>>(x, W1r, B, N, 129, 256);  // xr1 = B
  // fused edge phase; out aliases xr (block n reads only xr[n], writes only out[n])
  fused_gat_kernel<2><<<N, 256, 0, stream>>>(row_off, csr_src, A, B, a1, b1, B, N);
  float* h1 = B;

  // ---- layer 2: 256 -> 128 (H=1, C=128) ----
  float* xl2 = A;
  float* xr2 = A + (size_t)N*128;
  gemm_kernel<<<dim3((N+63)/64, 2), 256, 0, stream>>>(h1, W2l, xl2, N, 256, 128);
  gemm_kernel<<<dim3((N+63)/64, 2), 256, 0, stream>>>(h1, W2r, xr2, N, 256, 128);
  fused_gat_kernel<1><<<N, 128, 0, stream>>>(row_off, csr_src, xl2, xr2, a2, b2, xr2, N);
  float* h2 = xr2;

  // ---- layer 3: 128 -> 1 (H=1, C=1) ----
  float* xl3 = B;
  float* xr3 = B + N;
  float* h3  = B + 2*(size_t)N;
  gemm3_kernel<<<(N+3)/4, 256, 0, stream>>>(h2, W3l, W3r, xl3, xr3, N);
  aggr3_kernel<<<(N+255)/256, 256, 0, stream>>>(row_off, csr_src, xl3, xr3, a3, b3, h3, N);

  // ---- output: (sigmoid(h3)[tidx], y[tidx]) ----
  out_kernel<<<(T+255)/256, 256, 0, stream>>>(h3, y, tidx, (float*)d_out, T);
}

// Round 3
// 841.299 us; speedup vs baseline: 1.7255x; 1.4276x over previous
//
#include <hip/hip_runtime.h>
#include <cmath>

#define LEAKY(v) ((v) > 0.f ? (v) : 0.2f*(v))

// ---------------- CSR build ----------------

__global__ void deg_kernel(const int* __restrict__ dst, int* __restrict__ degi, int E){
  int e = blockIdx.x*256 + threadIdx.x;
  if (e < E) atomicAdd(&degi[dst[e]], 1);
}

__global__ void scan_kernel(const int* __restrict__ degi, int* __restrict__ row_off, int N){
  __shared__ int part[1024];
  int t = threadIdx.x;
  int chunk = (N + 1023) >> 10;
  int s0 = t*chunk, s1 = min(s0 + chunk, N);
  int sum = 0;
  for (int i = s0; i < s1; i++) sum += degi[i];
  part[t] = sum; __syncthreads();
  for (int off = 1; off < 1024; off <<= 1){
    int v = (t >= off) ? part[t - off] : 0;
    __syncthreads();
    part[t] += v;
    __syncthreads();
  }
  int run = (t == 0) ? 0 : part[t-1];
  for (int i = s0; i < s1; i++){ row_off[i] = run; run += degi[i]; }
  if (t == 1023) row_off[N] = run;
}

__global__ void scatter_kernel(const int* __restrict__ src, const int* __restrict__ dst,
                               const int* __restrict__ row_off, int* __restrict__ cursor,
                               int* __restrict__ csr_src, int E){
  int e = blockIdx.x*256 + threadIdx.x;
  if (e < E){
    int d = dst[e];
    int pos = row_off[d] + atomicAdd(&cursor[d], 1);
    csr_src[pos] = src[e];
  }
}

// ---------------- GEMM: O[N,M] = X[N,K] @ W[K,M]; 128x64 tile, 8x4 microtile ----------------

__global__ __launch_bounds__(256) void gemm_kernel(const float* __restrict__ X,
                                                   const float* __restrict__ W,
                                                   float* __restrict__ O,
                                                   int N, int K, int M){
  __shared__ float Xs[32][132];   // [k][r], pad 4 keeps float4 alignment, breaks store conflicts a bit
  __shared__ float Ws[32][64];    // [k][c]
  int t = threadIdx.x;
  int n0 = blockIdx.x*128, c0 = blockIdx.y*64;
  int tx = t & 15, ty = t >> 4;   // tx: 16 col-groups x4, ty: 16 row-groups x8
  float acc[8][4];
  #pragma unroll
  for (int i = 0; i < 8; i++)
    #pragma unroll
    for (int j = 0; j < 4; j++) acc[i][j] = 0.f;

  for (int k0 = 0; k0 < K; k0 += 32){
    // stage X tile: 128 rows x 32 k (coalesced along k)
    for (int idx = t; idx < 4096; idx += 256){
      int r = idx >> 5, kk = idx & 31;
      int n = n0 + r, k = k0 + kk;
      Xs[kk][r] = (n < N && k < K) ? X[(size_t)n*K + k] : 0.f;
    }
    // stage W tile: 32 k x 64 cols (coalesced along c)
    for (int idx = t; idx < 2048; idx += 256){
      int kk = idx >> 6, c = idx & 63;
      int k = k0 + kk;
      Ws[kk][c] = (k < K) ? W[(size_t)k*M + c0 + c] : 0.f;
    }
    __syncthreads();
    #pragma unroll
    for (int kk = 0; kk < 32; kk++){
      float4 xa = *(const float4*)&Xs[kk][ty*8];
      float4 xb = *(const float4*)&Xs[kk][ty*8+4];
      float4 wv = *(const float4*)&Ws[kk][tx*4];
      float xr_[8] = {xa.x,xa.y,xa.z,xa.w,xb.x,xb.y,xb.z,xb.w};
      #pragma unroll
      for (int i = 0; i < 8; i++){
        acc[i][0] += xr_[i]*wv.x;
        acc[i][1] += xr_[i]*wv.y;
        acc[i][2] += xr_[i]*wv.z;
        acc[i][3] += xr_[i]*wv.w;
      }
    }
    __syncthreads();
  }
  #pragma unroll
  for (int i = 0; i < 8; i++){
    int n = n0 + ty*8 + i;
    if (n < N){
      float4 v;
      v.x = acc[i][0]; v.y = acc[i][1]; v.z = acc[i][2]; v.w = acc[i][3];
      *(float4*)&O[(size_t)n*M + c0 + tx*4] = v;
    }
  }
}

// ---------------- fused GATv2 edge phase: wave-per-node, barrier-free ----------------
// H=2, CH=256: lane holds channels 4*lane..4*lane+3; lanes 0-31 = head 0, 32-63 = head 1.
// out may alias xr: wave n reads only xr row n, writes only out row n.

__global__ __launch_bounds__(256) void fused_gat_wave2(
    const int* __restrict__ row_off, const int* __restrict__ csr_src,
    const float* __restrict__ xl, const float* __restrict__ xr,
    const float* __restrict__ att, const float* __restrict__ bias,
    float* __restrict__ out, int N)
{
  int n = blockIdx.x*4 + (threadIdx.x >> 6);
  if (n >= N) return;
  int lane = threadIdx.x & 63;
  int r0 = row_off[n], r1 = row_off[n+1];
  const float4* xl4 = (const float4*)xl;
  float4 xrv = ((const float4*)xr)[(size_t)n*64 + lane];
  float4 attv = ((const float4*)att)[lane];
  float m = -INFINITY, l = 0.f;
  float4 acc = {0.f,0.f,0.f,0.f};

  int p = r0;
  int s = (p < r1) ? csr_src[p] : 0;
  float4 xv = (p < r1) ? xl4[(size_t)s*64 + lane] : acc;
  for (; p < r1; p++){
    // prefetch next edge's row while computing this one
    int s2 = (p+1 < r1) ? csr_src[p+1] : 0;
    float4 xn = xl4[(size_t)s2*64 + lane];
    float e0 = xv.x + xrv.x; e0 = LEAKY(e0);
    float e1 = xv.y + xrv.y; e1 = LEAKY(e1);
    float e2 = xv.z + xrv.z; e2 = LEAKY(e2);
    float e3 = xv.w + xrv.w; e3 = LEAKY(e3);
    float dot = e0*attv.x + e1*attv.y + e2*attv.z + e3*attv.w;
    dot += __shfl_xor(dot, 16);
    dot += __shfl_xor(dot, 8);
    dot += __shfl_xor(dot, 4);
    dot += __shfl_xor(dot, 2);
    dot += __shfl_xor(dot, 1);   // per-32-half sum -> per-head logit
    float nm = fmaxf(m, dot);
    float sc = __expf(m - nm);   // 0 on first edge (m = -inf)
    float w  = __expf(dot - nm);
    l = l*sc + w;
    acc.x = acc.x*sc + w*xv.x;
    acc.y = acc.y*sc + w*xv.y;
    acc.z = acc.z*sc + w*xv.z;
    acc.w = acc.w*sc + w*xv.w;
    m = nm;
    xv = xn;
  }
  float4 bv = ((const float4*)bias)[lane];
  float4 res = bv;
  if (r1 > r0){
    float inv = 1.f / (l * (float)(r1 - r0));
    res.x += acc.x*inv; res.y += acc.y*inv; res.z += acc.z*inv; res.w += acc.w*inv;
  }
  ((float4*)out)[(size_t)n*64 + lane] = res;
}

// H=1, CH=128: lane holds channels 2*lane..2*lane+1; reduce over all 64 lanes.
__global__ __launch_bounds__(256) void fused_gat_wave1(
    const int* __restrict__ row_off, const int* __restrict__ csr_src,
    const float* __restrict__ xl, const float* __restrict__ xr,
    const float* __restrict__ att, const float* __restrict__ bias,
    float* __restrict__ out, int N)
{
  int n = blockIdx.x*4 + (threadIdx.x >> 6);
  if (n >= N) return;
  int lane = threadIdx.x & 63;
  int r0 = row_off[n], r1 = row_off[n+1];
  const float2* xl2 = (const float2*)xl;
  float2 xrv = ((const float2*)xr)[(size_t)n*64 + lane];
  float2 attv = ((const float2*)att)[lane];
  float m = -INFINITY, l = 0.f;
  float2 acc = {0.f,0.f};

  int p = r0;
  int s = (p < r1) ? csr_src[p] : 0;
  float2 xv = (p < r1) ? xl2[(size_t)s*64 + lane] : acc;
  for (; p < r1; p++){
    int s2 = (p+1 < r1) ? csr_src[p+1] : 0;
    float2 xn = xl2[(size_t)s2*64 + lane];
    float e0 = xv.x + xrv.x; e0 = LEAKY(e0);
    float e1 = xv.y + xrv.y; e1 = LEAKY(e1);
    float dot = e0*attv.x + e1*attv.y;
    dot += __shfl_xor(dot, 32);
    dot += __shfl_xor(dot, 16);
    dot += __shfl_xor(dot, 8);
    dot += __shfl_xor(dot, 4);
    dot += __shfl_xor(dot, 2);
    dot += __shfl_xor(dot, 1);
    float nm = fmaxf(m, dot);
    float sc = __expf(m - nm);
    float w  = __expf(dot - nm);
    l = l*sc + w;
    acc.x = acc.x*sc + w*xv.x;
    acc.y = acc.y*sc + w*xv.y;
    m = nm;
    xv = xn;
  }
  float2 bv = ((const float2*)bias)[lane];
  float2 res = bv;
  if (r1 > r0){
    float inv = 1.f / (l * (float)(r1 - r0));
    res.x += acc.x*inv; res.y += acc.y*inv;
  }
  ((float2*)out)[(size_t)n*64 + lane] = res;
}

// ---------------- layer 3 (C=1) ----------------

__global__ __launch_bounds__(256) void gemm3_kernel(const float* __restrict__ h2,
                                                    const float* __restrict__ W3l,
                                                    const float* __restrict__ W3r,
                                                    float* __restrict__ xl3,
                                                    float* __restrict__ xr3, int N){
  int n = blockIdx.x*4 + (threadIdx.x >> 6);
  int lane = threadIdx.x & 63;
  if (n >= N) return;
  float v1 = h2[(size_t)n*128 + lane];
  float v2 = h2[(size_t)n*128 + 64 + lane];
  float al = v1*W3l[lane] + v2*W3l[64 + lane];
  float ar = v1*W3r[lane] + v2*W3r[64 + lane];
  #pragma unroll
  for (int off = 32; off > 0; off >>= 1){
    al += __shfl_down(al, off);
    ar += __shfl_down(ar, off);
  }
  if (lane == 0){ xl3[n] = al; xr3[n] = ar; }
}

// fused logits + online softmax + mean for C=1 (one thread per node, single pass)
__global__ void aggr3_kernel(const int* __restrict__ row_off, const int* __restrict__ csr_src,
                             const float* __restrict__ xl3, const float* __restrict__ xr3,
                             const float* __restrict__ a3, const float* __restrict__ b3,
                             float* __restrict__ h3, int N){
  int n = blockIdx.x*256 + threadIdx.x;
  if (n >= N) return;
  int r0 = row_off[n], r1 = row_off[n+1];
  int deg = r1 - r0;
  float b = b3[0];
  if (deg == 0){ h3[n] = b; return; }
  float xr = xr3[n];
  float aa = a3[0];
  float m = -INFINITY, den = 0.f, s = 0.f;
  for (int p = r0; p < r1; p++){
    float xlv = xl3[csr_src[p]];
    float v = xlv + xr;
    v = LEAKY(v) * aa;
    if (v > m){
      float sc = __expf(m - v);
      den *= sc; s *= sc; m = v;
    }
    float a = __expf(v - m);
    den += a;
    s += a * xlv;
  }
  h3[n] = s/den/(float)deg + b;
}

__global__ void out_kernel(const float* __restrict__ h3, const float* __restrict__ y,
                           const int* __restrict__ tidx, float* __restrict__ out, int T){
  int i = blockIdx.x*256 + threadIdx.x;
  if (i >= T) return;
  int n = tidx[i];
  out[i] = 1.f/(1.f + __expf(-h3[n]));
  out[T + i] = y[n];
}

// ---------------- launch ----------------

extern "C" void kernel_launch(void* const* d_in, const int* in_sizes, int n_in,
                              void* d_out, int out_size, void* d_ws, size_t ws_size,
                              hipStream_t stream){
  const float* x    = (const float*)d_in[0];
  const int*   ei   = (const int*)d_in[1];
  const float* y    = (const float*)d_in[2];
  const int*   tidx = (const int*)d_in[3];
  const float* W1l  = (const float*)d_in[4];
  const float* W1r  = (const float*)d_in[5];
  const float* a1   = (const float*)d_in[6];
  const float* b1   = (const float*)d_in[7];
  const float* W2l  = (const float*)d_in[8];
  const float* W2r  = (const float*)d_in[9];
  const float* a2   = (const float*)d_in[10];
  const float* b2   = (const float*)d_in[11];
  const float* W3l  = (const float*)d_in[12];
  const float* W3r  = (const float*)d_in[13];
  const float* a3   = (const float*)d_in[14];
  const float* b3   = (const float*)d_in[15];

  int N = in_sizes[2];        // 50000 nodes
  int E = in_sizes[1] / 2;    // 800000 edges
  int T = in_sizes[3];        // 40000 train indices
  const int* src = ei;
  const int* dst = ei + E;

  char* w = (char*)d_ws;
  size_t off = 0;
  auto take = [&](size_t bytes) -> char* {
    char* p = w + off;
    off = (off + bytes + 255) & ~(size_t)255;
    return p;
  };
  int*   row_off = (int*)  take((size_t)(N+1)*4);
  int*   degi    = (int*)  take((size_t)N*4);
  int*   cursor  = (int*)  take((size_t)N*4);
  int*   csr_src = (int*)  take((size_t)E*4);
  float* A       = (float*)take((size_t)N*256*4);
  float* B       = (float*)take((size_t)N*256*4);

  // ---- CSR build (graph shared by all 3 layers) ----
  hipMemsetAsync(degi, 0, (size_t)N*4, stream);
  hipMemsetAsync(cursor, 0, (size_t)N*4, stream);
  deg_kernel<<<(E+255)/256, 256, 0, stream>>>(dst, degi, E);
  scan_kernel<<<1, 1024, 0, stream>>>(degi, row_off, N);
  scatter_kernel<<<(E+255)/256, 256, 0, stream>>>(src, dst, row_off, cursor, csr_src, E);

  // ---- layer 1: 129 -> 256 (H=2, C=128) ----
  gemm_kernel<<<dim3((N+127)/128, 4), 256, 0, stream>>>(x, W1l, A, N, 129, 256);  // xl1 = A
  gemm_kernel<<<dim3((N+127)/128, 4), 256, 0, stream>>>(x, W1r, B, N, 129, 256);  // xr1 = B
  fused_gat_wave2<<<(N+3)/4, 256, 0, stream>>>(row_off, csr_src, A, B, a1, b1, B, N);
  float* h1 = B;

  // ---- layer 2: 256 -> 128 (H=1, C=128) ----
  float* xl2 = A;
  float* xr2 = A + (size_t)N*128;
  gemm_kernel<<<dim3((N+127)/128, 2), 256, 0, stream>>>(h1, W2l, xl2, N, 256, 128);
  gemm_kernel<<<dim3((N+127)/128, 2), 256, 0, stream>>>(h1, W2r, xr2, N, 256, 128);
  fused_gat_wave1<<<(N+3)/4, 256, 0, stream>>>(row_off, csr_src, xl2, xr2, a2, b2, xr2, N);
  float* h2 = xr2;

  // ---- layer 3: 128 -> 1 (H=1, C=1) ----
  float* xl3 = B;
  float* xr3 = B + N;
  float* h3  = B + 2*(size_t)N;
  gemm3_kernel<<<(N+3)/4, 256, 0, stream>>>(h2, W3l, W3r, xl3, xr3, N);
  aggr3_kernel<<<(N+255)/256, 256, 0, stream>>>(row_off, csr_src, xl3, xr3, a3, b3, h3, N);

  // ---- output: (sigmoid(h3)[tidx], y[tidx]) ----
  out_kernel<<<(T+255)/256, 256, 0, stream>>>(h3, y, tidx, (float*)d_out, T);
}